// Round 3
// baseline (443.865 us; speedup 1.0000x reference)
//
#include <hip/hip_runtime.h>
#include <hip/hip_bf16.h>

typedef __bf16 bf16;
typedef __bf16 bf16x8 __attribute__((ext_vector_type(8)));
typedef __bf16 bf16x4 __attribute__((ext_vector_type(4)));
typedef float  f32x4v __attribute__((ext_vector_type(4)));

#define MFMA16(a, b, c) __builtin_amdgcn_mfma_f32_16x16x32_bf16((a), (b), (c), 0, 0, 0)

static constexpr int D_MODEL = 1024;
static constexpr int NH      = 16;
static constexpr int DK      = 64;
static constexpr int BATCH   = 4;
static constexpr int SEQ     = 2048;

// async global->LDS, 16B per lane; LDS dest = wave-uniform base + lane*16
__device__ __forceinline__ void glds16(const void* g, void* l) {
    __builtin_amdgcn_global_load_lds((const __attribute__((address_space(1))) void*)g,
                                     (__attribute__((address_space(3))) void*)l, 16, 0, 0);
}

// ---------------------------------------------------------------------------
// fp32 -> bf16 bulk convert, 7 tensors in one launch (blockIdx.y selects)
// ---------------------------------------------------------------------------
struct CvtArgs {
    const float* s[7];
    bf16* d[7];
    int n[7];
};

__global__ __launch_bounds__(256) void cvt7(CvtArgs a) {
    const int which = blockIdx.y;
    const int i = (blockIdx.x * 256 + threadIdx.x) * 8;
    if (i >= a.n[which]) return;
    const float4 v0 = *(const float4*)(a.s[which] + i);
    const float4 v1 = *(const float4*)(a.s[which] + i + 4);
    bf16x8 o = {(bf16)v0.x, (bf16)v0.y, (bf16)v0.z, (bf16)v0.w,
                (bf16)v1.x, (bf16)v1.y, (bf16)v1.z, (bf16)v1.w};
    *(bf16x8*)(a.d[which] + i) = o;
}

// ---------------------------------------------------------------------------
// mask int32 [S][S] -> bf16 ADDITIVE bias [S][S] with 4-way column interleave
// per 64-group: Mr[row][g*64 + l15*4 + ch] = bias(mask[row][g*64 + ch*16 + l15])
// bias = 0 (keep) or -16384 (masked; exact in bf16, exp2 underflows to 0).
// An attn lane reads its 4 chunk-values (cols kt+ch*16+l15) as one 8B load.
// ---------------------------------------------------------------------------
__global__ __launch_bounds__(256) void mask_prep(const int* __restrict__ m,
                                                 bf16* __restrict__ Mr) {
    const int o = blockIdx.x * 256 + threadIdx.x;  // 0 .. S*S-1
    const int row = o >> 11, j = o & 2047;
    const int g = j >> 6, idx = j & 63;
    const int incol = (g << 6) + ((idx & 3) << 4) + (idx >> 2);
    Mr[o] = m[row * 2048 + incol] ? (bf16)0.0f : (bf16)-16384.0f;
}

// ---------------------------------------------------------------------------
// C = A @ W^T + bias. A: [8192][1024] bf16 row-major, W: [1024][1024] bf16
// row-major ([N][K] => B^T form). 128x128 tile, BK=32, global_load_lds(16B)
// staging into packed LDS, 2-barrier m97-style K-loop, 4 waves of 64x64.
// Grid: 1-D 512 blocks with XCD panel-clustered swizzle: the 8 n-tiles that
// share one A m-panel all land on the SAME XCD (L%8 = panel group), so the
// 256 KB A-panel is fetched into that XCD's L2 once instead of 8 times.
// MODE 0: head-major bf16 [b][h][s][dk];
// MODE 1: V^T bf16 [b][h][dk][s] with 4-way interleave of s within each
//         64-group: pos p = (s%16)*4 + (s%64)/16  (matches mask/P layout);
// MODE 2: fp32 row-major [M][1024].
// ---------------------------------------------------------------------------
template <int MODE>
__global__ __launch_bounds__(256) void gemm_bt(const bf16* __restrict__ A,
                                               const bf16* __restrict__ W,
                                               const float* __restrict__ bias,
                                               void* __restrict__ outv) {
    __shared__ bf16 Als[128 * 32];  // packed row-major, stride 32 bf16 (64 B)
    __shared__ bf16 Bls[128 * 32];

    const int tid  = threadIdx.x;
    const int wave = tid >> 6;
    const int lane = tid & 63;
    const int l15  = lane & 15;
    const int quad = lane >> 4;
    // XCD swizzle: L bits [2:0]=a, [5:3]=b, [8:6]=c.  m-tile = a + 8c (64),
    // n-tile = b (8).  Same m-tile => same a => same XCD (hw: linear%8).
    const int L    = blockIdx.x;
    const int m0   = ((L & 7) | ((L >> 6) << 3)) * 128;
    const int n0   = ((L >> 3) & 7) * 128;
    const int wm   = (wave >> 1) * 64;
    const int wn   = (wave & 1) * 64;

    f32x4v acc[4][4];
#pragma unroll
    for (int i = 0; i < 4; ++i)
#pragma unroll
        for (int j = 0; j < 4; ++j) acc[i][j] = (f32x4v){0.f, 0.f, 0.f, 0.f};

    // staging map: slot = p*256 + wave*64 + lane; row = slot>>2, chunk = slot&3
    const int r_a    = wave * 16 + (lane >> 2);
    const int c_a    = (lane & 3) * 8;
    const int ldsoff = wave * 512;  // elements; + p*2048

    for (int k0 = 0; k0 < 1024; k0 += 32) {
        __syncthreads();
#pragma unroll
        for (int p = 0; p < 2; ++p) {
            const int row = p * 64 + r_a;
            glds16(A + (size_t)(m0 + row) * 1024 + k0 + c_a, &Als[p * 2048 + ldsoff]);
            glds16(W + (size_t)(n0 + row) * 1024 + k0 + c_a, &Bls[p * 2048 + ldsoff]);
        }
        __syncthreads();

        bf16x8 af[4], bfr[4];
#pragma unroll
        for (int i = 0; i < 4; ++i)
            af[i] = *(const bf16x8*)(&Als[(wm + i * 16 + l15) * 32 + quad * 8]);
#pragma unroll
        for (int j = 0; j < 4; ++j)
            bfr[j] = *(const bf16x8*)(&Bls[(wn + j * 16 + l15) * 32 + quad * 8]);
#pragma unroll
        for (int i = 0; i < 4; ++i)
#pragma unroll
            for (int j = 0; j < 4; ++j) acc[i][j] = MFMA16(af[i], bfr[j], acc[i][j]);
    }

    // epilogue: C/D layout col = lane&15, row = quad*4 + reg
#pragma unroll
    for (int j = 0; j < 4; ++j) {
        const int col = n0 + wn + j * 16 + l15;
        const float bs = bias[col];
        const int h = col >> 6, dk = col & 63;
        if (MODE == 1) {
            // V^T interleaved: within the 64-row group starting at m0+wm, the
            // value for logical s-offset o = quad*4+reg + i*16 goes to physical
            // position p = (quad*4+reg)*4 + i  -> the 4 i-values are contiguous.
            bf16* out = (bf16*)outv;
            const int sg = m0 + wm;               // 64-aligned
            const int bb = sg >> 11, sb = sg & 2047;
            const size_t rowbase = ((size_t)((bb * NH + h) * 64 + dk)) * SEQ + sb;
#pragma unroll
            for (int reg = 0; reg < 4; ++reg) {
                bf16x4 v = {(bf16)(acc[0][j][reg] + bs), (bf16)(acc[1][j][reg] + bs),
                            (bf16)(acc[2][j][reg] + bs), (bf16)(acc[3][j][reg] + bs)};
                *(bf16x4*)(&out[rowbase + (quad * 4 + reg) * 4]) = v;
            }
        } else {
#pragma unroll
            for (int i = 0; i < 4; ++i) {
                const int r4 = m0 + wm + i * 16 + quad * 4;
                const int b = r4 >> 11, sb = r4 & 2047;
                if (MODE == 2) {
                    float* out = (float*)outv;
#pragma unroll
                    for (int reg = 0; reg < 4; ++reg)
                        out[(size_t)(r4 + reg) * 1024 + col] = acc[i][j][reg] + bs;
                } else {  // MODE 0
                    bf16* out = (bf16*)outv;
#pragma unroll
                    for (int reg = 0; reg < 4; ++reg)
                        out[((size_t)(b * NH + h) * SEQ + sb + reg) * 64 + dk] =
                            (bf16)(acc[i][j][reg] + bs);
                }
            }
        }
    }
}

// ---------------------------------------------------------------------------
// Flash attention, fixed-max softmax (exact here: e = exp2(s*c + mbias); mbias
// is 0 or -16384 so masked terms are exactly 0, matching -1e9 ref; scores
// bounded so no overflow). Block = 2 waves x 64 q-rows = 128 rows; key tiles
// of 64.  QBLK=128 (round-3): grid 1024 blocks = exactly 4 blocks/CU (LDS
// 34.8 KB allows 4) -> 4 independent barrier domains per CU so one block's
// softmax-VALU phase overlaps another's MFMA phase (was grid-capped at 2).
// K head-major [bh][s][64]; V^T [bh][64][s] k-INTERLEAVED within each
// 64-group (p = (s%16)*4 + (s%64)/16) so the PV K-axis permutation matches P.
// Softmax: e written as packed bf16x4 -> ds_write_b64.
// Row sums via an extra ones-MFMA pair per row-block (C-layout puts the sum
// at sacc[rb][reg] in every lane -> no shuffle reduction, no scalar adds).
// VGPR must stay <= 128 (occupancy halves past 128 — round-1 lesson).
// ---------------------------------------------------------------------------
__global__ __launch_bounds__(128, 4) void attn_kernel(const bf16* __restrict__ Qh,
                                                      const bf16* __restrict__ Kh,
                                                      const bf16* __restrict__ Vtg,
                                                      const bf16* __restrict__ Mr,
                                                      bf16* __restrict__ Xout) {
    __shared__ bf16 Kls[4096];       // 8 chunks x 64 keys x 8 bf16
    __shared__ bf16 Vls[4096];       // 8 chunks x 64 d    x 8 bf16
    __shared__ bf16 Pls[128 * 72];   // 2 waves x 64 rows, stride 72 (144B)

    const int tid  = threadIdx.x;
    const int wave = tid >> 6;       // 0..1
    const int lane = tid & 63;
    const int l15  = lane & 15;
    const int quad = lane >> 4;
    const int bh   = blockIdx.x;     // blocks sharing bh are stride-64 apart
                                     // in linear id => same XCD already
    const int q0   = blockIdx.y * 128;

    const size_t base = (size_t)bh * SEQ * DK;
    const bf16* Q  = Qh + base;
    const bf16* K  = Kh + base;
    const bf16* Vg = Vtg + base;  // [64][SEQ], s interleaved per 64-group

    const int qw = q0 + wave * 64;
    bf16x8 aq[4][2];
#pragma unroll
    for (int rb = 0; rb < 4; ++rb)
#pragma unroll
        for (int hf = 0; hf < 2; ++hf)
            aq[rb][hf] = *(const bf16x8*)(Q + (size_t)(qw + rb * 16 + l15) * 64 +
                                          hf * 32 + quad * 8);

    bf16x8 ones;
#pragma unroll
    for (int t = 0; t < 8; ++t) ones[t] = (bf16)1.0f;

    f32x4v acc[4][4];  // [rb][nt] PV accumulators
    f32x4v sacc[4];    // [rb] row-sum accumulators (denominator)
#pragma unroll
    for (int rb = 0; rb < 4; ++rb) {
        sacc[rb] = (f32x4v){0.f, 0.f, 0.f, 0.f};
#pragma unroll
        for (int x = 0; x < 4; ++x) acc[rb][x] = (f32x4v){0.f, 0.f, 0.f, 0.f};
    }

    constexpr float CLOG = 0.125f * 1.4426950408889634f;  // scale * log2(e)
    const bf16* mbase = Mr + (size_t)(qw + quad * 4) * 2048 + l15 * 4;

    for (int kt = 0; kt < SEQ; kt += 64) {
        __syncthreads();  // all waves done reading prev K/V tiles
#pragma unroll
        for (int p = 0; p < 4; ++p) {
            const int kc = wave * 4 + p;
            glds16(K + (size_t)(kt + lane) * 64 + kc * 8, &Kls[kc * 512]);
            glds16(Vg + (size_t)lane * SEQ + kt + kc * 8, &Vls[kc * 512]);
        }
        // additive mask bias (bf16, 8B loads) issued before the barrier drain
        bf16x4 mv[4][4];
#pragma unroll
        for (int rb = 0; rb < 4; ++rb)
#pragma unroll
            for (int reg = 0; reg < 4; ++reg)
                mv[rb][reg] =
                    *(const bf16x4*)(mbase + (size_t)(rb * 16 + reg) * 2048 + kt);
        __syncthreads();

        // K B-frags (shared across the wave's 4 row-blocks)
        bf16x8 bk[4][2];
#pragma unroll
        for (int n16 = 0; n16 < 4; ++n16)
#pragma unroll
            for (int kk = 0; kk < 2; ++kk)
                bk[n16][kk] = *(const bf16x8*)(&Kls[((kk * 4 + quad) * 64 + n16 * 16 + l15) * 8]);

#pragma unroll
        for (int rb = 0; rb < 4; ++rb) {
            f32x4v sv[4];
            __builtin_amdgcn_s_setprio(1);
#pragma unroll
            for (int n16 = 0; n16 < 4; ++n16) {
                f32x4v t = (f32x4v){0.f, 0.f, 0.f, 0.f};
                t = MFMA16(aq[rb][0], bk[n16][0], t);
                t = MFMA16(aq[rb][1], bk[n16][1], t);
                sv[n16] = t;
            }
            __builtin_amdgcn_s_setprio(0);
            const int prow0 = wave * 64 + rb * 16 + quad * 4;
#pragma unroll
            for (int reg = 0; reg < 4; ++reg) {
                const float e0 = exp2f(fmaf(sv[0][reg], CLOG, (float)mv[rb][reg][0]));
                const float e1 = exp2f(fmaf(sv[1][reg], CLOG, (float)mv[rb][reg][1]));
                const float e2 = exp2f(fmaf(sv[2][reg], CLOG, (float)mv[rb][reg][2]));
                const float e3 = exp2f(fmaf(sv[3][reg], CLOG, (float)mv[rb][reg][3]));
                // interleaved physical position: lane's 4 n16-values contiguous
                bf16x4 p4 = {(bf16)e0, (bf16)e1, (bf16)e2, (bf16)e3};
                *(bf16x4*)(&Pls[(prow0 + reg) * 72 + l15 * 4]) = p4;
            }
        }

        // P A-frags (same-wave LDS round trip; compiler inserts lgkmcnt waits)
        bf16x8 pf[4][2];
#pragma unroll
        for (int rb = 0; rb < 4; ++rb)
#pragma unroll
            for (int kc2 = 0; kc2 < 2; ++kc2)
                pf[rb][kc2] = *(const bf16x8*)(&Pls[(wave * 64 + rb * 16 + l15) * 72 +
                                                    kc2 * 32 + quad * 8]);

        __builtin_amdgcn_s_setprio(1);
        // row sums: sacc[rb][reg] += sum_k P[row][k]  (every column identical)
#pragma unroll
        for (int rb = 0; rb < 4; ++rb) {
            sacc[rb] = MFMA16(pf[rb][0], ones, sacc[rb]);
            sacc[rb] = MFMA16(pf[rb][1], ones, sacc[rb]);
        }
        // O += P V   (V staged with the SAME k-interleave -> consistent K axis)
#pragma unroll
        for (int nt = 0; nt < 4; ++nt) {
            const bf16x8 bv0 = *(const bf16x8*)(&Vls[(quad * 64 + nt * 16 + l15) * 8]);
            const bf16x8 bv1 = *(const bf16x8*)(&Vls[((4 + quad) * 64 + nt * 16 + l15) * 8]);
#pragma unroll
            for (int rb = 0; rb < 4; ++rb) {
                acc[rb][nt] = MFMA16(pf[rb][0], bv0, acc[rb][nt]);
                acc[rb][nt] = MFMA16(pf[rb][1], bv1, acc[rb][nt]);
            }
        }
        __builtin_amdgcn_s_setprio(0);
    }

    // normalize and write X row-major bf16 [B*S][D_MODEL]
    const int b = bh >> 4, h = bh & 15;
#pragma unroll
    for (int rb = 0; rb < 4; ++rb) {
        float rinv[4];
#pragma unroll
        for (int reg = 0; reg < 4; ++reg) rinv[reg] = 1.0f / sacc[rb][reg];
#pragma unroll
        for (int nt = 0; nt < 4; ++nt)
#pragma unroll
            for (int reg = 0; reg < 4; ++reg) {
                const int sg = qw + rb * 16 + quad * 4 + reg;
                Xout[(size_t)(b * SEQ + sg) * D_MODEL + h * 64 + nt * 16 + l15] =
                    (bf16)(acc[rb][nt][reg] * rinv[reg]);
            }
    }
}

extern "C" void kernel_launch(void* const* d_in, const int* in_sizes, int n_in,
                              void* d_out, int out_size, void* d_ws, size_t ws_size,
                              hipStream_t stream) {
    const float* q    = (const float*)d_in[0];
    const float* k    = (const float*)d_in[1];
    const float* v    = (const float*)d_in[2];
    const int*   mask = (const int*)d_in[3];
    const float* Wq   = (const float*)d_in[4];
    const float* bq   = (const float*)d_in[5];
    const float* Wk   = (const float*)d_in[6];
    const float* bk   = (const float*)d_in[7];
    const float* Wv   = (const float*)d_in[8];
    const float* bv   = (const float*)d_in[9];
    const float* Wo   = (const float*)d_in[10];
    const float* bo   = (const float*)d_in[11];

    const size_t T = (size_t)BATCH * SEQ * D_MODEL;  // 8,388,608
    const size_t WN = (size_t)D_MODEL * D_MODEL;     // 1,048,576
    char* w = (char*)d_ws;
    bf16* Qh  = (bf16*)w;            w += T * 2;
    bf16* Kh  = (bf16*)w;            w += T * 2;
    bf16* Vt  = (bf16*)w;            w += T * 2;
    bf16* Mr  = (bf16*)w;            w += (size_t)SEQ * SEQ * 2;
    bf16* qb  = (bf16*)w;            w += T * 2;   // reused as X after gemmQ
    bf16* kb  = (bf16*)w;            w += T * 2;
    bf16* vb  = (bf16*)w;            w += T * 2;
    bf16* Wqb = (bf16*)w;            w += WN * 2;
    bf16* Wkb = (bf16*)w;            w += WN * 2;
    bf16* Wvb = (bf16*)w;            w += WN * 2;
    bf16* Wob = (bf16*)w;            w += WN * 2;  // total ~112 MiB

    CvtArgs ca;
    ca.s[0] = q;  ca.d[0] = qb;  ca.n[0] = (int)T;
    ca.s[1] = k;  ca.d[1] = kb;  ca.n[1] = (int)T;
    ca.s[2] = v;  ca.d[2] = vb;  ca.n[2] = (int)T;
    ca.s[3] = Wq; ca.d[3] = Wqb; ca.n[3] = (int)WN;
    ca.s[4] = Wk; ca.d[4] = Wkb; ca.n[4] = (int)WN;
    ca.s[5] = Wv; ca.d[5] = Wvb; ca.n[5] = (int)WN;
    ca.s[6] = Wo; ca.d[6] = Wob; ca.n[6] = (int)WN;

    cvt7<<<dim3(4096, 7), 256, 0, stream>>>(ca);
    mask_prep<<<dim3((SEQ * SEQ) / 256), 256, 0, stream>>>(mask, Mr);

    dim3 gg(512);  // 1-D grid, XCD panel-clustered swizzle inside
    gemm_bt<0><<<gg, 256, 0, stream>>>(qb, Wqb, bq, (void*)Qh);
    gemm_bt<0><<<gg, 256, 0, stream>>>(kb, Wkb, bk, (void*)Kh);
    gemm_bt<1><<<gg, 256, 0, stream>>>(vb, Wvb, bv, (void*)Vt);

    attn_kernel<<<dim3(BATCH * NH, SEQ / 128), 128, 0, stream>>>(Qh, Kh, Vt, Mr, qb);

    gemm_bt<2><<<gg, 256, 0, stream>>>(qb, Wob, bo, d_out);
}

// Round 4
// 391.668 us; speedup vs baseline: 1.1333x; 1.1333x over previous
//
#include <hip/hip_runtime.h>
#include <hip/hip_bf16.h>

typedef __bf16 bf16;
typedef __bf16 bf16x8 __attribute__((ext_vector_type(8)));
typedef __bf16 bf16x4 __attribute__((ext_vector_type(4)));
typedef float  f32x4v __attribute__((ext_vector_type(4)));

#define MFMA16(a, b, c) __builtin_amdgcn_mfma_f32_16x16x32_bf16((a), (b), (c), 0, 0, 0)

static constexpr int D_MODEL = 1024;
static constexpr int NH      = 16;
static constexpr int DK      = 64;
static constexpr int BATCH   = 4;
static constexpr int SEQ     = 2048;

// async global->LDS, 16B per lane; LDS dest = wave-uniform base + lane*16
__device__ __forceinline__ void glds16(const void* g, void* l) {
    __builtin_amdgcn_global_load_lds((const __attribute__((address_space(1))) void*)g,
                                     (__attribute__((address_space(3))) void*)l, 16, 0, 0);
}

// ---------------------------------------------------------------------------
// fp32 -> bf16 bulk convert, 7 tensors in one launch (blockIdx.y selects)
// ---------------------------------------------------------------------------
struct CvtArgs {
    const float* s[7];
    bf16* d[7];
    int n[7];
};

__global__ __launch_bounds__(256) void cvt7(CvtArgs a) {
    const int which = blockIdx.y;
    const int i = (blockIdx.x * 256 + threadIdx.x) * 8;
    if (i >= a.n[which]) return;
    const float4 v0 = *(const float4*)(a.s[which] + i);
    const float4 v1 = *(const float4*)(a.s[which] + i + 4);
    bf16x8 o = {(bf16)v0.x, (bf16)v0.y, (bf16)v0.z, (bf16)v0.w,
                (bf16)v1.x, (bf16)v1.y, (bf16)v1.z, (bf16)v1.w};
    *(bf16x8*)(a.d[which] + i) = o;
}

// ---------------------------------------------------------------------------
// mask int32 [S][S] -> bf16 ADDITIVE bias [S][S], column order permuted within
// each 64-group to pos(s) = quad(s)*16 + n(s)*4 + r(s)  where
// s = 16*n + 4*quad + r.  An attn lane (l15, quad) then reads its 16 values
// (k = n*16 + quad*4 + r, n,r in 0..3) as TWO contiguous 16B loads.
// bias = 0 (keep) or -16384 (masked; exact in bf16, exp2 underflows to 0).
// ---------------------------------------------------------------------------
__global__ __launch_bounds__(256) void mask_prep(const int* __restrict__ m,
                                                 bf16* __restrict__ Mr) {
    const int o = blockIdx.x * 256 + threadIdx.x;  // 0 .. S*S-1
    const int row = o >> 11, j = o & 2047;
    const int g = j >> 6, idx = j & 63;  // idx = pos
    // invert pos: quad = idx>>4, n = (idx>>2)&3, r = idx&3 ; s = 16n+4quad+r
    const int incol = (g << 6) + (((idx >> 2) & 3) << 4) + ((idx >> 4) << 2) + (idx & 3);
    Mr[o] = m[row * 2048 + incol] ? (bf16)0.0f : (bf16)-16384.0f;
}

// ---------------------------------------------------------------------------
// C = A @ W^T + bias. A: [8192][1024] bf16 row-major, W: [1024][1024] bf16
// row-major ([N][K] => B^T form). 128x128 tile, BK=32, global_load_lds(16B)
// staging into packed LDS, 2-barrier m97-style K-loop, 4 waves of 64x64.
// Grid: 1-D 512 blocks with XCD panel-clustered swizzle: the 8 n-tiles that
// share one A m-panel all land on the SAME XCD (L%8 = panel group), so the
// 256 KB A-panel is fetched into that XCD's L2 once instead of 8 times.
// MODE 0: head-major bf16 [b][h][s][dk];
// MODE 1: V^T bf16 [b][h][dk][s] with s permuted within each 64-group:
//         pos(s) = quad(s)*16 + n(s)*4 + r(s), s = 16n+4quad+r (matches mask
//         and the attn PV k-axis).  Store stays vectorized: for fixed i the
//         4 reg-values are contiguous (pos = quad*16 + i*4 + reg).
// MODE 2: fp32 row-major [M][1024].
// ---------------------------------------------------------------------------
template <int MODE>
__global__ __launch_bounds__(256) void gemm_bt(const bf16* __restrict__ A,
                                               const bf16* __restrict__ W,
                                               const float* __restrict__ bias,
                                               void* __restrict__ outv) {
    __shared__ bf16 Als[128 * 32];  // packed row-major, stride 32 bf16 (64 B)
    __shared__ bf16 Bls[128 * 32];

    const int tid  = threadIdx.x;
    const int wave = tid >> 6;
    const int lane = tid & 63;
    const int l15  = lane & 15;
    const int quad = lane >> 4;
    // XCD swizzle: L bits [2:0]=a, [5:3]=b, [8:6]=c.  m-tile = a + 8c (64),
    // n-tile = b (8).  Same m-tile => same a => same XCD (hw: linear%8).
    const int L    = blockIdx.x;
    const int m0   = ((L & 7) | ((L >> 6) << 3)) * 128;
    const int n0   = ((L >> 3) & 7) * 128;
    const int wm   = (wave >> 1) * 64;
    const int wn   = (wave & 1) * 64;

    f32x4v acc[4][4];
#pragma unroll
    for (int i = 0; i < 4; ++i)
#pragma unroll
        for (int j = 0; j < 4; ++j) acc[i][j] = (f32x4v){0.f, 0.f, 0.f, 0.f};

    // staging map: slot = p*256 + wave*64 + lane; row = slot>>2, chunk = slot&3
    const int r_a    = wave * 16 + (lane >> 2);
    const int c_a    = (lane & 3) * 8;
    const int ldsoff = wave * 512;  // elements; + p*2048

    for (int k0 = 0; k0 < 1024; k0 += 32) {
        __syncthreads();
#pragma unroll
        for (int p = 0; p < 2; ++p) {
            const int row = p * 64 + r_a;
            glds16(A + (size_t)(m0 + row) * 1024 + k0 + c_a, &Als[p * 2048 + ldsoff]);
            glds16(W + (size_t)(n0 + row) * 1024 + k0 + c_a, &Bls[p * 2048 + ldsoff]);
        }
        __syncthreads();

        bf16x8 af[4], bfr[4];
#pragma unroll
        for (int i = 0; i < 4; ++i)
            af[i] = *(const bf16x8*)(&Als[(wm + i * 16 + l15) * 32 + quad * 8]);
#pragma unroll
        for (int j = 0; j < 4; ++j)
            bfr[j] = *(const bf16x8*)(&Bls[(wn + j * 16 + l15) * 32 + quad * 8]);
#pragma unroll
        for (int i = 0; i < 4; ++i)
#pragma unroll
            for (int j = 0; j < 4; ++j) acc[i][j] = MFMA16(af[i], bfr[j], acc[i][j]);
    }

    // epilogue: C/D layout col = lane&15, row = quad*4 + reg
#pragma unroll
    for (int j = 0; j < 4; ++j) {
        const int col = n0 + wn + j * 16 + l15;
        const float bs = bias[col];
        const int h = col >> 6, dk = col & 63;
        if (MODE == 1) {
            // logical s-offset o = i*16 + quad*4 + reg  ->  pos = quad*16+i*4+reg
            // so for fixed i the 4 reg-values are contiguous: bf16x4 store.
            bf16* out = (bf16*)outv;
            const int sg = m0 + wm;               // 64-aligned
            const int bb = sg >> 11, sb = sg & 2047;
            const size_t rowbase = ((size_t)((bb * NH + h) * 64 + dk)) * SEQ + sb;
#pragma unroll
            for (int i = 0; i < 4; ++i) {
                bf16x4 v = {(bf16)(acc[i][j][0] + bs), (bf16)(acc[i][j][1] + bs),
                            (bf16)(acc[i][j][2] + bs), (bf16)(acc[i][j][3] + bs)};
                *(bf16x4*)(&out[rowbase + quad * 16 + i * 4]) = v;
            }
        } else {
#pragma unroll
            for (int i = 0; i < 4; ++i) {
                const int r4 = m0 + wm + i * 16 + quad * 4;
                const int b = r4 >> 11, sb = r4 & 2047;
                if (MODE == 2) {
                    float* out = (float*)outv;
#pragma unroll
                    for (int reg = 0; reg < 4; ++reg)
                        out[(size_t)(r4 + reg) * 1024 + col] = acc[i][j][reg] + bs;
                } else {  // MODE 0
                    bf16* out = (bf16*)outv;
#pragma unroll
                    for (int reg = 0; reg < 4; ++reg)
                        out[((size_t)(b * NH + h) * SEQ + sb + reg) * 64 + dk] =
                            (bf16)(acc[i][j][reg] + bs);
                }
            }
        }
    }
}

// ---------------------------------------------------------------------------
// Flash attention, fixed-max softmax (exact: e = exp2(s*c + mbias); mbias is
// 0 or -16384 so masked terms are exactly 0, matching -1e9 ref).
// Block = 4 waves x 64 q-rows = 256 rows; key tiles of 64.
//
// SWAPPED QK^T (round-4): compute mfma(K, Q) — for 16x16x32 the A- and
// B-frag lane mappings are identical, so aq/ak register contents are
// unchanged; only operand order flips.  Output S[k][q] has q = l15: each
// lane's 16 scores belong to ITS OWN q-row, which is exactly the PV
// A-fragment layout.  The PV A-frags are therefore built by pure in-register
// packing of the exp2 results — the P LDS round-trip (16 ds_write_b64 +
// 8 ds_read_b128 + 18KB Pls + lgkm serialization per tile-wave) is GONE.
// The induced k-axis permutation pos(s)=quad*16+n*4+r is baked into the
// V^T global layout (gemm MODE 1) and the mask layout, so PV's A and B
// k-axes agree.  Row sums still via ones-MFMA; output layout unchanged.
// VGPR will exceed 128; grid caps residency at 8 waves/CU which ~170 VGPR
// still permits (launch_bounds(256,2)).
// ---------------------------------------------------------------------------
__global__ __launch_bounds__(256, 2) void attn_kernel(const bf16* __restrict__ Qh,
                                                      const bf16* __restrict__ Kh,
                                                      const bf16* __restrict__ Vtg,
                                                      const bf16* __restrict__ Mr,
                                                      bf16* __restrict__ Xout) {
    __shared__ bf16 Kls[4096];       // 8 chunks x 64 keys x 8 bf16
    __shared__ bf16 Vls[4096];       // 8 chunks x 64 d    x 8 bf16

    const int tid  = threadIdx.x;
    const int wave = tid >> 6;
    const int lane = tid & 63;
    const int l15  = lane & 15;
    const int quad = lane >> 4;
    const int bh   = blockIdx.x;
    const int q0   = blockIdx.y * 256;

    const size_t base = (size_t)bh * SEQ * DK;
    const bf16* Q  = Qh + base;
    const bf16* K  = Kh + base;
    const bf16* Vg = Vtg + base;  // [64][SEQ], s permuted per 64-group

    const int qw = q0 + wave * 64;
    bf16x8 aq[4][2];
#pragma unroll
    for (int rb = 0; rb < 4; ++rb)
#pragma unroll
        for (int kk = 0; kk < 2; ++kk)
            aq[rb][kk] = *(const bf16x8*)(Q + (size_t)(qw + rb * 16 + l15) * 64 +
                                          kk * 32 + quad * 8);

    bf16x8 ones;
#pragma unroll
    for (int t = 0; t < 8; ++t) ones[t] = (bf16)1.0f;

    f32x4v acc[4][4];  // [rb][nt] PV accumulators
    f32x4v sacc[4];    // [rb] row-sum accumulators (denominator)
#pragma unroll
    for (int rb = 0; rb < 4; ++rb) {
        sacc[rb] = (f32x4v){0.f, 0.f, 0.f, 0.f};
#pragma unroll
        for (int x = 0; x < 4; ++x) acc[rb][x] = (f32x4v){0.f, 0.f, 0.f, 0.f};
    }

    constexpr float CLOG = 0.125f * 1.4426950408889634f;  // scale * log2(e)
    // lane's mask row is its own q-row: qw + rb*16 + l15 ; col base quad*16
    const bf16* mbase = Mr + (size_t)(qw + l15) * 2048 + quad * 16;

    for (int kt = 0; kt < SEQ; kt += 64) {
        __syncthreads();  // all waves done reading prev K/V tiles
#pragma unroll
        for (int p = 0; p < 2; ++p) {
            const int kc = wave * 2 + p;
            glds16(K + (size_t)(kt + lane) * 64 + kc * 8, &Kls[kc * 512]);
            glds16(Vg + (size_t)lane * SEQ + kt + kc * 8, &Vls[kc * 512]);
        }
        // additive mask bias: per rb, 16 contiguous bf16 = 2 x 16B loads
        bf16x8 mv[4][2];
#pragma unroll
        for (int rb = 0; rb < 4; ++rb)
#pragma unroll
            for (int h2 = 0; h2 < 2; ++h2)
                mv[rb][h2] = *(const bf16x8*)(mbase + (size_t)(rb * 16) * 2048 +
                                              kt + h2 * 8);
        __syncthreads();

        // K frags (A operand of swapped QK^T; same lane mapping as before)
        bf16x8 ak[4][2];
#pragma unroll
        for (int n16 = 0; n16 < 4; ++n16)
#pragma unroll
            for (int kk = 0; kk < 2; ++kk)
                ak[n16][kk] = *(const bf16x8*)(&Kls[((kk * 4 + quad) * 64 + n16 * 16 + l15) * 8]);

        // QK^T (swapped) + softmax -> in-register PV A-frags
        bf16x8 pa[4][2];  // [rb][g], element j=nlow*4+reg <-> k=16*(2g+nlow)+4quad+reg
#pragma unroll
        for (int rb = 0; rb < 4; ++rb) {
            f32x4v sv[4];
            __builtin_amdgcn_s_setprio(1);
#pragma unroll
            for (int n16 = 0; n16 < 4; ++n16) {
                f32x4v t = (f32x4v){0.f, 0.f, 0.f, 0.f};
                t = MFMA16(ak[n16][0], aq[rb][0], t);   // S[k][q], q = l15
                t = MFMA16(ak[n16][1], aq[rb][1], t);
                sv[n16] = t;
            }
            __builtin_amdgcn_s_setprio(0);
#pragma unroll
            for (int n16 = 0; n16 < 4; ++n16)
#pragma unroll
                for (int reg = 0; reg < 4; ++reg) {
                    const float e = exp2f(fmaf(sv[n16][reg], CLOG,
                                               (float)mv[rb][n16 >> 1][(n16 & 1) * 4 + reg]));
                    pa[rb][n16 >> 1][(n16 & 1) * 4 + reg] = (bf16)e;
                }
        }

        __builtin_amdgcn_s_setprio(1);
        // row sums: sacc[rb][reg] += sum_k P[q][k]  (every column identical)
#pragma unroll
        for (int rb = 0; rb < 4; ++rb) {
            sacc[rb] = MFMA16(pa[rb][0], ones, sacc[rb]);
            sacc[rb] = MFMA16(pa[rb][1], ones, sacc[rb]);
        }
        // O += P V  (V staged with the SAME k-permutation -> axes agree)
#pragma unroll
        for (int nt = 0; nt < 4; ++nt) {
            const bf16x8 bv0 = *(const bf16x8*)(&Vls[((quad * 2 + 0) * 64 + nt * 16 + l15) * 8]);
            const bf16x8 bv1 = *(const bf16x8*)(&Vls[((quad * 2 + 1) * 64 + nt * 16 + l15) * 8]);
#pragma unroll
            for (int rb = 0; rb < 4; ++rb) {
                acc[rb][nt] = MFMA16(pa[rb][0], bv0, acc[rb][nt]);
                acc[rb][nt] = MFMA16(pa[rb][1], bv1, acc[rb][nt]);
            }
        }
        __builtin_amdgcn_s_setprio(0);
    }

    // normalize and write X row-major bf16 [B*S][D_MODEL]
    const int b = bh >> 4, h = bh & 15;
#pragma unroll
    for (int rb = 0; rb < 4; ++rb) {
        float rinv[4];
#pragma unroll
        for (int reg = 0; reg < 4; ++reg) rinv[reg] = 1.0f / sacc[rb][reg];
#pragma unroll
        for (int nt = 0; nt < 4; ++nt)
#pragma unroll
            for (int reg = 0; reg < 4; ++reg) {
                const int sg = qw + rb * 16 + quad * 4 + reg;
                Xout[(size_t)(b * SEQ + sg) * D_MODEL + h * 64 + nt * 16 + l15] =
                    (bf16)(acc[rb][nt][reg] * rinv[reg]);
            }
    }
}

extern "C" void kernel_launch(void* const* d_in, const int* in_sizes, int n_in,
                              void* d_out, int out_size, void* d_ws, size_t ws_size,
                              hipStream_t stream) {
    const float* q    = (const float*)d_in[0];
    const float* k    = (const float*)d_in[1];
    const float* v    = (const float*)d_in[2];
    const int*   mask = (const int*)d_in[3];
    const float* Wq   = (const float*)d_in[4];
    const float* bq   = (const float*)d_in[5];
    const float* Wk   = (const float*)d_in[6];
    const float* bk   = (const float*)d_in[7];
    const float* Wv   = (const float*)d_in[8];
    const float* bv   = (const float*)d_in[9];
    const float* Wo   = (const float*)d_in[10];
    const float* bo   = (const float*)d_in[11];

    const size_t T = (size_t)BATCH * SEQ * D_MODEL;  // 8,388,608
    const size_t WN = (size_t)D_MODEL * D_MODEL;     // 1,048,576
    char* w = (char*)d_ws;
    bf16* Qh  = (bf16*)w;            w += T * 2;
    bf16* Kh  = (bf16*)w;            w += T * 2;
    bf16* Vt  = (bf16*)w;            w += T * 2;
    bf16* Mr  = (bf16*)w;            w += (size_t)SEQ * SEQ * 2;
    bf16* qb  = (bf16*)w;            w += T * 2;   // reused as X after gemmQ
    bf16* kb  = (bf16*)w;            w += T * 2;
    bf16* vb  = (bf16*)w;            w += T * 2;
    bf16* Wqb = (bf16*)w;            w += WN * 2;
    bf16* Wkb = (bf16*)w;            w += WN * 2;
    bf16* Wvb = (bf16*)w;            w += WN * 2;
    bf16* Wob = (bf16*)w;            w += WN * 2;  // total ~112 MiB

    CvtArgs ca;
    ca.s[0] = q;  ca.d[0] = qb;  ca.n[0] = (int)T;
    ca.s[1] = k;  ca.d[1] = kb;  ca.n[1] = (int)T;
    ca.s[2] = v;  ca.d[2] = vb;  ca.n[2] = (int)T;
    ca.s[3] = Wq; ca.d[3] = Wqb; ca.n[3] = (int)WN;
    ca.s[4] = Wk; ca.d[4] = Wkb; ca.n[4] = (int)WN;
    ca.s[5] = Wv; ca.d[5] = Wvb; ca.n[5] = (int)WN;
    ca.s[6] = Wo; ca.d[6] = Wob; ca.n[6] = (int)WN;

    cvt7<<<dim3(4096, 7), 256, 0, stream>>>(ca);
    mask_prep<<<dim3((SEQ * SEQ) / 256), 256, 0, stream>>>(mask, Mr);

    dim3 gg(512);  // 1-D grid, XCD panel-clustered swizzle inside
    gemm_bt<0><<<gg, 256, 0, stream>>>(qb, Wqb, bq, (void*)Qh);
    gemm_bt<0><<<gg, 256, 0, stream>>>(kb, Wkb, bk, (void*)Kh);
    gemm_bt<1><<<gg, 256, 0, stream>>>(vb, Wvb, bv, (void*)Vt);

    attn_kernel<<<dim3(BATCH * NH, SEQ / 256), 256, 0, stream>>>(Qh, Kh, Vt, Mr, qb);

    gemm_bt<2><<<gg, 256, 0, stream>>>(qb, Wob, bo, d_out);
}